// Round 11
// baseline (165.856 us; speedup 1.0000x reference)
//
#include <hip/hip_runtime.h>
#include <cstdint>

#pragma clang fp contract(off)

typedef float v2f __attribute__((ext_vector_type(2)));

#define P_N 2048
#define F_N 8192
#define TPB 256
#define FPT 32
#define NT (F_N / FPT)
#define TW 32          // tab row floats (21 used, 128B row)
#define CHUNK 256      // faces staged per chunk in k_solve
#define NCHUNK (F_N / CHUNK)
#define QCAP 768

// ---- workspace layout ----
#define WS_PTAB_OFF ((size_t)F_N * TW * 4)             // tab = 1 MB
#define WS_NEEDED   (WS_PTAB_OFF + (size_t)F_N * 16)   // + ptab 128 KB

// =============== exact helpers (bit-identical to reference, proven R1-R10) ===============

__device__ __forceinline__ void face_setup(
    const float* __restrict__ vertices, const int* __restrict__ faces, int f,
    float* fd)
{
#pragma clang fp contract(off)
    int i0 = faces[3 * f + 0];
    int i1 = faces[3 * f + 1];
    int i2 = faces[3 * f + 2];
    float ax = vertices[3 * i0 + 0], ay = vertices[3 * i0 + 1], az = vertices[3 * i0 + 2];
    float bx = vertices[3 * i1 + 0], by = vertices[3 * i1 + 1], bz = vertices[3 * i1 + 2];
    float cx = vertices[3 * i2 + 0], cy = vertices[3 * i2 + 1], cz = vertices[3 * i2 + 2];
    float abx = bx - ax, aby = by - ay, abz = bz - az;
    float acx = cx - ax, acy = cy - ay, acz = cz - az;
    float daab = (ax * abx + ay * aby) + az * abz;
    float daac = (ax * acx + ay * acy) + az * acz;
    float dbab = (bx * abx + by * aby) + bz * abz;
    float dbac = (bx * acx + by * acy) + bz * acz;
    float dcab = (cx * abx + cy * aby) + cz * abz;
    float dcac = (cx * acx + cy * acy) + cz * acz;
    fd[0] = ax;  fd[1] = ay;  fd[2] = az;
    fd[3] = bx;  fd[4] = by;  fd[5] = bz;
    fd[6] = cx;  fd[7] = cy;  fd[8] = cz;
    fd[9] = abx; fd[10] = aby; fd[11] = abz;
    fd[12] = acx; fd[13] = acy; fd[14] = acz;
    fd[15] = daab; fd[16] = daac; fd[17] = dbab;
    fd[18] = dbac; fd[19] = dcab; fd[20] = dcac;
}

// full 5-divide exact tree (bit-exact w's and dist)
__device__ __forceinline__ void tri_eval_exact(
    float px, float py, float pz,
    const float* __restrict__ fd,
    float& w1o, float& w2o, float& w3o, float& disto)
{
#pragma clang fp contract(off)
    const float ax = fd[0], ay = fd[1], az = fd[2];
    const float bx = fd[3], by = fd[4], bz = fd[5];
    const float cx = fd[6], cy = fd[7], cz = fd[8];
    const float abx = fd[9], aby = fd[10], abz = fd[11];
    const float acx = fd[12], acy = fd[13], acz = fd[14];
    const float daab = fd[15], daac = fd[16], dbab = fd[17];
    const float dbac = fd[18], dcab = fd[19], dcac = fd[20];

    float pab = fmaf(pz, abz, fmaf(py, aby, px * abx));
    float pac = fmaf(pz, acz, fmaf(py, acy, px * acx));

    float d1 = pab - daab;
    float d2 = pac - daac;
    float d3 = pab - dbab;
    float d4 = pac - dbac;
    float d5 = pab - dcab;
    float d6 = pac - dcac;

    float vc = d1 * d4 - d3 * d2;
    float vb = d5 * d2 - d1 * d6;
    float va = d3 * d6 - d5 * d4;

    float denom = (va + vb) + vc;
    float dn = (denom == 0.0f) ? 1.0f : denom;
    float v7 = vb / dn;
    float w7 = vc / dn;
    float w1 = (1.0f - v7) - w7;
    float w2 = v7;
    float w3 = w7;

    float e63 = d4 - d3;
    float e65 = d5 - d6;
    float t6d = e63 + e65; t6d = (t6d == 0.0f) ? 1.0f : t6d;
    float t6 = e63 / t6d;
    if ((va <= 0.0f) & (e63 >= 0.0f) & (e65 >= 0.0f)) { w1 = 0.0f; w2 = 1.0f - t6; w3 = t6; }

    float t5d = d2 - d6; t5d = (t5d == 0.0f) ? 1.0f : t5d;
    float t5 = d2 / t5d;
    if ((vb <= 0.0f) & (d2 >= 0.0f) & (d6 <= 0.0f)) { w1 = 1.0f - t5; w2 = 0.0f; w3 = t5; }

    if ((d6 >= 0.0f) & (d5 <= d6)) { w1 = 0.0f; w2 = 0.0f; w3 = 1.0f; }

    float t3d = d1 - d3; t3d = (t3d == 0.0f) ? 1.0f : t3d;
    float t3 = d1 / t3d;
    if ((vc <= 0.0f) & (d1 >= 0.0f) & (d3 <= 0.0f)) { w1 = 1.0f - t3; w2 = t3; w3 = 0.0f; }

    if ((d3 >= 0.0f) & (d4 <= d3)) { w1 = 0.0f; w2 = 1.0f; w3 = 0.0f; }

    if ((d1 <= 0.0f) & (d2 <= 0.0f)) { w1 = 1.0f; w2 = 0.0f; w3 = 0.0f; }

    float cpx = (w1 * ax + w2 * bx) + w3 * cx;
    float cpy = (w1 * ay + w2 * by) + w3 * cy;
    float cpz = (w1 * az + w2 * bz) + w3 * cz;
    float dx = px - cpx, dy = py - cpy, dz = pz - cpz;
    float dist = (dx * dx + dy * dy) + dz * dz;

    w1o = w1; w2o = w2; w3o = w3; disto = dist;
}

// 2-divide region path (R4/R5-proven: dist bit-identical to reference)
__device__ __forceinline__ void region_w(
    float d1, float d2, float d3, float d4, float d5, float d6,
    float va, float vb, float vc, float e63, float e65, float denom,
    float& w1, float& w2, float& w3)
{
#pragma clang fp contract(off)
    bool m1 = (d1 <= 0.0f) & (d2 <= 0.0f);
    bool m2 = (d3 >= 0.0f) & (d4 <= d3);
    bool m3 = (vc <= 0.0f) & (d1 >= 0.0f) & (d3 <= 0.0f);
    bool m4 = (d6 >= 0.0f) & (d5 <= d6);
    bool m5 = (vb <= 0.0f) & (d2 >= 0.0f) & (d6 <= 0.0f);
    bool m6 = (va <= 0.0f) & (e63 >= 0.0f) & (e65 >= 0.0f);
    bool anym = m1 | m2 | m3 | m4 | m5 | m6;

    float n1  = m1 ? 0.0f : m2 ? 0.0f : m3 ? d1        : m4 ? 0.0f : m5 ? d2        : m6 ? e63         : vb;
    float ds1 = m1 ? 1.0f : m2 ? 1.0f : m3 ? (d1 - d3) : m4 ? 1.0f : m5 ? (d2 - d6) : m6 ? (e63 + e65) : denom;
    ds1 = (ds1 == 0.0f) ? 1.0f : ds1;
    float n2  = anym ? 0.0f : vc;
    float ds2 = anym ? 1.0f : ((denom == 0.0f) ? 1.0f : denom);

    float q1 = n1 / ds1;
    float q2 = n2 / ds2;
    float u = (1.0f - q1) - q2;

    w1 = m1 ? 1.0f : m2 ? 0.0f : m3 ? u    : m4 ? 0.0f : m5 ? u    : m6 ? 0.0f : u;
    w2 = m1 ? 0.0f : m2 ? 1.0f : m3 ? q1   : m4 ? 0.0f : m5 ? 0.0f : m6 ? u    : q1;
    w3 = m1 ? 0.0f : m2 ? 0.0f : m3 ? 0.0f : m4 ? 1.0f : m5 ? q1   : m6 ? q1   : q2;
}

__device__ __forceinline__ float tri_dist_region(
    float px, float py, float pz, const float* __restrict__ fd)
{
#pragma clang fp contract(off)
    const float ax = fd[0], ay = fd[1], az = fd[2];
    const float bx = fd[3], by = fd[4], bz = fd[5];
    const float cx = fd[6], cy = fd[7], cz = fd[8];
    const float abx = fd[9], aby = fd[10], abz = fd[11];
    const float acx = fd[12], acy = fd[13], acz = fd[14];
    const float daab = fd[15], daac = fd[16], dbab = fd[17];
    const float dbac = fd[18], dcab = fd[19], dcac = fd[20];

    float pab = fmaf(pz, abz, fmaf(py, aby, px * abx));
    float pac = fmaf(pz, acz, fmaf(py, acy, px * acx));

    float d1 = pab - daab;
    float d2 = pac - daac;
    float d3 = pab - dbab;
    float d4 = pac - dbac;
    float d5 = pab - dcab;
    float d6 = pac - dcac;

    float vc = d1 * d4 - d3 * d2;
    float vb = d5 * d2 - d1 * d6;
    float va = d3 * d6 - d5 * d4;

    float e63 = d4 - d3;
    float e65 = d5 - d6;
    float denom = (va + vb) + vc;

    float w1, w2, w3;
    region_w(d1, d2, d3, d4, d5, d6, va, vb, vc, e63, e65, denom, w1, w2, w3);

    float cpx = (w1 * ax + w2 * bx) + w3 * cx;
    float cpy = (w1 * ay + w2 * by) + w3 * cy;
    float cpz = (w1 * az + w2 * bz) + w3 * cz;
    float dx = px - cpx, dy = py - cpy, dz = pz - cpz;
    return (dx * dx + dy * dy) + dz * dz;
}

// =============== k_prep: exact const table + compact plane table ===============

__global__ __launch_bounds__(TPB) void k_prep(
    const float* __restrict__ vertices, const int* __restrict__ faces,
    float* __restrict__ tab, float4* __restrict__ ptab)
{
#pragma clang fp contract(off)
    int f = blockIdx.x * TPB + threadIdx.x;
    if (f >= F_N) return;

    float td[TW];
    face_setup(vertices, faces, f, td);
    float ax = td[0], ay = td[1], az = td[2];
    float abx = td[9], aby = td[10], abz = td[11];
    float acx = td[12], acy = td[13], acz = td[14];
    float nx = aby * acz - abz * acy;
    float ny = abz * acx - abx * acz;
    float nz = abx * acy - aby * acx;
    float nn = (nx * nx + ny * ny) + nz * nz;
    float abab = (abx * abx + aby * aby) + abz * abz;
    float acac = (acx * acx + acy * acy) + acz * acz;
    float L2v = abab + acac;
    bool bad = !(nn >= 1e-2f * L2v) || (nn < 1e-20f);

    float mnd = -((nx * ax + ny * ay) + nz * az);
    float s = bad ? 0.0f : sqrtf(1.0f / nn);
    // unit-normal plane: nd = sn.p + smnd ; bad faces -> all zeros -> p2 = 0 (always candidate)
    ptab[f] = make_float4(nx * s, ny * s, nz * s, mnd * s);

    td[21] = 0.0f; td[22] = 0.0f; td[23] = 0.0f;
    td[24] = 0.0f; td[25] = 0.0f; td[26] = 0.0f; td[27] = 0.0f;
    td[28] = 0.0f; td[29] = 0.0f; td[30] = 0.0f; td[31] = 0.0f;
#pragma unroll
    for (int k = 0; k < TW; k += 4)
        *(float4*)&tab[f * TW + k] = *(float4*)&td[k];
}

// =============== k_solve: one wave per point, fully in-wave ===============

__device__ __forceinline__ int lbcode(float x)
{
    int c = (int)(__float_as_uint(x) >> 20) - 896;  // monotone floor map for x >= 0
    return c < 0 ? 0 : (c > 255 ? 255 : c);
}

__global__ __launch_bounds__(TPB) void k_solve(
    const float* __restrict__ points,
    const float* __restrict__ tab,
    const float4* __restrict__ ptab,
    float* __restrict__ out)
{
    __shared__ float4 sfp[CHUNK];                     // 4 KB staged plane chunk
    __shared__ unsigned char codes[4][F_N];           // 32 KB LB codes (per wave)
    __shared__ unsigned short qb[4][QCAP];            // 6 KB queues
    __shared__ int qcnt[4];

    const int w = threadIdx.x >> 6;
    const int lane = threadIdx.x & 63;
    const int tid = threadIdx.x;
    const int p = blockIdx.x * 4 + w;

    if (lane == 0) qcnt[w] = 0;

    const float px = points[3 * p + 0];
    const float py = points[3 * p + 1];
    const float pz = points[3 * p + 2];

    // ---- pass A: plane^2 for all faces; champion track; u8 LB codes to LDS ----
    float bestp2 = 3e38f;
    int bj = lane;

    for (int c = 0; c < NCHUNK; ++c) {
        __syncthreads();
        sfp[tid] = ptab[c * CHUNK + tid];
        __syncthreads();
#pragma unroll
        for (int k = 0; k < CHUNK / 64; ++k) {
            int fl = k * 64 + lane;
            float4 sn = sfp[fl];
            float nd = fmaf(sn.z, pz, fmaf(sn.y, py, fmaf(sn.x, px, sn.w)));
            float p2 = nd * nd;
            int f = c * CHUNK + fl;
            bool better = p2 < bestp2;            // NaN -> false
            bestp2 = better ? p2 : bestp2;
            bj = better ? f : bj;
            float lb = fmaxf(fmaf(p2, 0.97f, -1e-6f), 0.0f);  // sound LB; NaN -> 0
            codes[w][f] = (unsigned char)lbcode(lb);
        }
    }

    // ---- champion exact eval -> thr = wave-min of 64 true distances (sound UB) ----
    float thrl;
    {
        float fd[21];
        const float* __restrict__ tf = tab + (size_t)bj * TW;
#pragma unroll
        for (int k = 0; k < 20; k += 4)
            *(float4*)&fd[k] = *(const float4*)&tf[k];
        fd[20] = tf[20];
        float dch = tri_dist_region(px, py, pz, fd);
        thrl = (dch != dch) ? 3e38f : dch;
    }
#pragma unroll
    for (int off = 32; off > 0; off >>= 1)
        thrl = fminf(thrl, __shfl_xor(thrl, off, 64));
    const unsigned thrcode = (unsigned)lbcode(thrl);  // floor map both sides -> no misses

    __syncthreads();

    // ---- pass B: scan codes, enqueue candidates ----
    const unsigned* __restrict__ cw = (const unsigned*)&codes[w][0];
    for (int it = 0; it < F_N / 256; ++it) {          // 32 iters
        unsigned word = cw[it * 64 + lane];
#pragma unroll
        for (int b = 0; b < 4; ++b) {
            unsigned cd = (word >> (8 * b)) & 255u;
            if (cd <= thrcode) {
                int s = atomicAdd(&qcnt[w], 1);
                if (s < QCAP) qb[w][s] = (unsigned short)((it * 64 + lane) * 4 + b);
            }
        }
    }
    __syncthreads();
    const int n = qcnt[w];

    // ---- exact eval of candidates, wave-min reduce, winner writes out ----
    unsigned long long bk = ~0ull;
    float bw1 = 0.0f, bw2 = 0.0f, bw3 = 0.0f;

    auto evalf = [&](int f) {
        float fdl[21];
        const float* __restrict__ tf = tab + (size_t)f * TW;
#pragma unroll
        for (int k = 0; k < 20; k += 4)
            *(float4*)&fdl[k] = *(const float4*)&tf[k];
        fdl[20] = tf[20];
        float w1, w2, w3, dist;
        tri_eval_exact(px, py, pz, fdl, w1, w2, w3, dist);
        unsigned db = __float_as_uint(dist);
        if (dist != dist) db = 0u;  // NaN -> -inf (numpy argmin: first NaN wins)
        unsigned long long key = ((unsigned long long)db << 32) | (unsigned)f;
        if (key < bk) { bk = key; bw1 = w1; bw2 = w2; bw3 = w3; }
    };

    if (n == 0 || n > QCAP) {
        for (int f = lane; f < F_N; f += 64) evalf(f);   // overflow / NaN fallback
    } else {
        for (int r = lane; r < n; r += 64) evalf((int)qb[w][r]);
    }

    unsigned long long red = bk;
#pragma unroll
    for (int off = 32; off > 0; off >>= 1) {
        unsigned long long o = __shfl_xor(red, off, 64);
        red = o < red ? o : red;
    }
    if (bk == red && red != ~0ull) {   // unique winner: keys embed distinct face ids
        int f = (int)(red & 0xffffffffull);
        out[p] = (float)f;
        out[P_N + p] = bw1;
        out[2 * P_N + p] = bw2;
        out[3 * P_N + p] = bw3;
    }
}

// =============== fallback: proven R5 full scan (tiny ws only) ===============

__global__ __launch_bounds__(TPB) void k_scan_full(
    const float* __restrict__ points,
    const float* __restrict__ vertices,
    const int* __restrict__ faces,
    unsigned long long* __restrict__ best)
{
#pragma clang fp contract(off)
    __shared__ float sq[21][FPT];
    const int pblk = blockIdx.x, fblk = blockIdx.y, t = threadIdx.x;
    if (t < FPT) {
        float fd[21];
        face_setup(vertices, faces, fblk * FPT + t, fd);
#pragma unroll
        for (int k = 0; k < 21; ++k) sq[k][t] = fd[k];
    }
    __syncthreads();

    const int p = pblk * TPB + t;
    const float px = points[3 * p], py = points[3 * p + 1], pz = points[3 * p + 2];
    const v2f pxv = {px, px}, pyv = {py, py}, pzv = {pz, pz};

    unsigned int bestdb = 0xffffffffu;
    int bestf = 0;
    const int fbase = fblk * FPT;

#pragma unroll 2
    for (int j = 0; j < FPT; j += 2) {
#define LD2(q) (*(const v2f*)&sq[q][j])
        v2f axv = LD2(0),  ayv = LD2(1),  azv = LD2(2);
        v2f bxv = LD2(3),  byv = LD2(4),  bzv = LD2(5);
        v2f cxv = LD2(6),  cyv = LD2(7),  czv = LD2(8);
        v2f abxv = LD2(9),  abyv = LD2(10), abzv = LD2(11);
        v2f acxv = LD2(12), acyv = LD2(13), aczv = LD2(14);
        v2f daabv = LD2(15), daacv = LD2(16), dbabv = LD2(17);
        v2f dbacv = LD2(18), dcabv = LD2(19), dcacv = LD2(20);
#undef LD2
        v2f pab = __builtin_elementwise_fma(pzv, abzv,
                    __builtin_elementwise_fma(pyv, abyv, pxv * abxv));
        v2f pac = __builtin_elementwise_fma(pzv, aczv,
                    __builtin_elementwise_fma(pyv, acyv, pxv * acxv));
        v2f d1 = pab - daabv, d2 = pac - daacv, d3 = pab - dbabv;
        v2f d4 = pac - dbacv, d5 = pab - dcabv, d6 = pac - dcacv;
        v2f vcv = d1 * d4 - d3 * d2;
        v2f vbv = d5 * d2 - d1 * d6;
        v2f vav = d3 * d6 - d5 * d4;
        v2f e63 = d4 - d3, e65 = d5 - d6;
        v2f denom = (vav + vbv) + vcv;

        float w1a, w2a, w3a, w1b, w2b, w3b;
        region_w(d1.x, d2.x, d3.x, d4.x, d5.x, d6.x,
                 vav.x, vbv.x, vcv.x, e63.x, e65.x, denom.x, w1a, w2a, w3a);
        region_w(d1.y, d2.y, d3.y, d4.y, d5.y, d6.y,
                 vav.y, vbv.y, vcv.y, e63.y, e65.y, denom.y, w1b, w2b, w3b);

        v2f w1v = {w1a, w1b}, w2v = {w2a, w2b}, w3v = {w3a, w3b};
        v2f cpx = (w1v * axv + w2v * bxv) + w3v * cxv;
        v2f cpy = (w1v * ayv + w2v * byv) + w3v * cyv;
        v2f cpz = (w1v * azv + w2v * bzv) + w3v * czv;
        v2f dx = pxv - cpx, dy = pyv - cpy, dz = pzv - cpz;
        v2f dist = (dx * dx + dy * dy) + dz * dz;

        float da = dist.x, db = dist.y;
        unsigned ua = __float_as_uint(da), ub = __float_as_uint(db);
        if (da != da) ua = 0u;
        if (db != db) ub = 0u;
        if (ua < bestdb) { bestdb = ua; bestf = fbase + j; }
        if (ub < bestdb) { bestdb = ub; bestf = fbase + j + 1; }
    }

    unsigned long long key =
        ((unsigned long long)bestdb << 32) | (unsigned int)bestf;
    atomicMin(&best[p], key);
}

__global__ __launch_bounds__(TPB) void k_final(
    const float* __restrict__ points,
    const float* __restrict__ vertices,
    const int* __restrict__ faces,
    const unsigned long long* __restrict__ best,
    float* __restrict__ out)
{
    const int p = blockIdx.x * TPB + threadIdx.x;
    if (p >= P_N) return;
    int f = (int)(best[p] & 0x1fffull);
    float fd[21];
    face_setup(vertices, faces, f, fd);
    float w1, w2, w3, dist;
    tri_eval_exact(points[3 * p], points[3 * p + 1], points[3 * p + 2],
                   fd, w1, w2, w3, dist);
    out[p] = (float)f;
    out[P_N + p] = w1;
    out[2 * P_N + p] = w2;
    out[3 * P_N + p] = w3;
}

extern "C" void kernel_launch(void* const* d_in, const int* in_sizes, int n_in,
                              void* d_out, int out_size, void* d_ws, size_t ws_size,
                              hipStream_t stream)
{
    const float* points = (const float*)d_in[0];
    const float* vertices = (const float*)d_in[1];
    const int* faces = (const int*)d_in[2];
    float* out = (float*)d_out;
    char* ws = (char*)d_ws;

    if (ws_size >= WS_NEEDED) {
        float* tab = (float*)ws;
        float4* ptab = (float4*)(ws + WS_PTAB_OFF);
        k_prep<<<F_N / TPB, TPB, 0, stream>>>(vertices, faces, tab, ptab);
        k_solve<<<P_N / 4, TPB, 0, stream>>>(points, tab, ptab, out);
    } else {
        unsigned long long* best = (unsigned long long*)ws;
        hipMemsetAsync(best, 0xFF, P_N * sizeof(unsigned long long), stream);
        k_scan_full<<<dim3(P_N / TPB, NT), TPB, 0, stream>>>(points, vertices, faces, best);
        k_final<<<(P_N + TPB - 1) / TPB, TPB, 0, stream>>>(points, vertices, faces, best, out);
    }
}

// Round 12
// 88.061 us; speedup vs baseline: 1.8834x; 1.8834x over previous
//
#include <hip/hip_runtime.h>
#include <cstdint>

#pragma clang fp contract(off)

typedef float v2f __attribute__((ext_vector_type(2)));

#define P_N 2048
#define F_N 8192
#define TPB 256
#define FPT 32
#define NT (F_N / FPT)
#define TW 32   // 0-20 exact consts; 21 nx 22 ny 23 nz 24 mnd 25 inn; 26-31 pad (128B row)

// ---- workspace layout ----
#define WS_TAB_BYTES   (F_N * TW * 4)                  // 1 MB
#define WS_MINUB_OFF   WS_TAB_BYTES
#define WS_BEST_OFF    (WS_MINUB_OFF + P_N * 4)
#define WS_SPTS_OFF    (WS_BEST_OFF + P_N * 8)
#define WS_NEEDED      (WS_SPTS_OFF + P_N * 16)

// =============== exact helpers (bit-identical to reference, proven R1-R11) ===============

__device__ __forceinline__ void face_setup(
    const float* __restrict__ vertices, const int* __restrict__ faces, int f,
    float* fd)
{
#pragma clang fp contract(off)
    int i0 = faces[3 * f + 0];
    int i1 = faces[3 * f + 1];
    int i2 = faces[3 * f + 2];
    float ax = vertices[3 * i0 + 0], ay = vertices[3 * i0 + 1], az = vertices[3 * i0 + 2];
    float bx = vertices[3 * i1 + 0], by = vertices[3 * i1 + 1], bz = vertices[3 * i1 + 2];
    float cx = vertices[3 * i2 + 0], cy = vertices[3 * i2 + 1], cz = vertices[3 * i2 + 2];
    float abx = bx - ax, aby = by - ay, abz = bz - az;
    float acx = cx - ax, acy = cy - ay, acz = cz - az;
    float daab = (ax * abx + ay * aby) + az * abz;
    float daac = (ax * acx + ay * acy) + az * acz;
    float dbab = (bx * abx + by * aby) + bz * abz;
    float dbac = (bx * acx + by * acy) + bz * acz;
    float dcab = (cx * abx + cy * aby) + cz * abz;
    float dcac = (cx * acx + cy * acy) + cz * acz;
    fd[0] = ax;  fd[1] = ay;  fd[2] = az;
    fd[3] = bx;  fd[4] = by;  fd[5] = bz;
    fd[6] = cx;  fd[7] = cy;  fd[8] = cz;
    fd[9] = abx; fd[10] = aby; fd[11] = abz;
    fd[12] = acx; fd[13] = acy; fd[14] = acz;
    fd[15] = daab; fd[16] = daac; fd[17] = dbab;
    fd[18] = dbac; fd[19] = dcab; fd[20] = dcac;
}

// full 5-divide exact tree (bit-exact w's and dist)
__device__ __forceinline__ void tri_eval_exact(
    float px, float py, float pz,
    const float* __restrict__ fd,
    float& w1o, float& w2o, float& w3o, float& disto)
{
#pragma clang fp contract(off)
    const float ax = fd[0], ay = fd[1], az = fd[2];
    const float bx = fd[3], by = fd[4], bz = fd[5];
    const float cx = fd[6], cy = fd[7], cz = fd[8];
    const float abx = fd[9], aby = fd[10], abz = fd[11];
    const float acx = fd[12], acy = fd[13], acz = fd[14];
    const float daab = fd[15], daac = fd[16], dbab = fd[17];
    const float dbac = fd[18], dcab = fd[19], dcac = fd[20];

    float pab = fmaf(pz, abz, fmaf(py, aby, px * abx));
    float pac = fmaf(pz, acz, fmaf(py, acy, px * acx));

    float d1 = pab - daab;
    float d2 = pac - daac;
    float d3 = pab - dbab;
    float d4 = pac - dbac;
    float d5 = pab - dcab;
    float d6 = pac - dcac;

    float vc = d1 * d4 - d3 * d2;
    float vb = d5 * d2 - d1 * d6;
    float va = d3 * d6 - d5 * d4;

    float denom = (va + vb) + vc;
    float dn = (denom == 0.0f) ? 1.0f : denom;
    float v7 = vb / dn;
    float w7 = vc / dn;
    float w1 = (1.0f - v7) - w7;
    float w2 = v7;
    float w3 = w7;

    float e63 = d4 - d3;
    float e65 = d5 - d6;
    float t6d = e63 + e65; t6d = (t6d == 0.0f) ? 1.0f : t6d;
    float t6 = e63 / t6d;
    if ((va <= 0.0f) & (e63 >= 0.0f) & (e65 >= 0.0f)) { w1 = 0.0f; w2 = 1.0f - t6; w3 = t6; }

    float t5d = d2 - d6; t5d = (t5d == 0.0f) ? 1.0f : t5d;
    float t5 = d2 / t5d;
    if ((vb <= 0.0f) & (d2 >= 0.0f) & (d6 <= 0.0f)) { w1 = 1.0f - t5; w2 = 0.0f; w3 = t5; }

    if ((d6 >= 0.0f) & (d5 <= d6)) { w1 = 0.0f; w2 = 0.0f; w3 = 1.0f; }

    float t3d = d1 - d3; t3d = (t3d == 0.0f) ? 1.0f : t3d;
    float t3 = d1 / t3d;
    if ((vc <= 0.0f) & (d1 >= 0.0f) & (d3 <= 0.0f)) { w1 = 1.0f - t3; w2 = t3; w3 = 0.0f; }

    if ((d3 >= 0.0f) & (d4 <= d3)) { w1 = 0.0f; w2 = 1.0f; w3 = 0.0f; }

    if ((d1 <= 0.0f) & (d2 <= 0.0f)) { w1 = 1.0f; w2 = 0.0f; w3 = 0.0f; }

    float cpx = (w1 * ax + w2 * bx) + w3 * cx;
    float cpy = (w1 * ay + w2 * by) + w3 * cy;
    float cpz = (w1 * az + w2 * bz) + w3 * cz;
    float dx = px - cpx, dy = py - cpy, dz = pz - cpz;
    float dist = (dx * dx + dy * dy) + dz * dz;

    w1o = w1; w2o = w2; w3o = w3; disto = dist;
}

// 2-divide region path (R4/R5-proven: dist bit-identical to reference)
__device__ __forceinline__ void region_w(
    float d1, float d2, float d3, float d4, float d5, float d6,
    float va, float vb, float vc, float e63, float e65, float denom,
    float& w1, float& w2, float& w3)
{
#pragma clang fp contract(off)
    bool m1 = (d1 <= 0.0f) & (d2 <= 0.0f);
    bool m2 = (d3 >= 0.0f) & (d4 <= d3);
    bool m3 = (vc <= 0.0f) & (d1 >= 0.0f) & (d3 <= 0.0f);
    bool m4 = (d6 >= 0.0f) & (d5 <= d6);
    bool m5 = (vb <= 0.0f) & (d2 >= 0.0f) & (d6 <= 0.0f);
    bool m6 = (va <= 0.0f) & (e63 >= 0.0f) & (e65 >= 0.0f);
    bool anym = m1 | m2 | m3 | m4 | m5 | m6;

    float n1  = m1 ? 0.0f : m2 ? 0.0f : m3 ? d1        : m4 ? 0.0f : m5 ? d2        : m6 ? e63         : vb;
    float ds1 = m1 ? 1.0f : m2 ? 1.0f : m3 ? (d1 - d3) : m4 ? 1.0f : m5 ? (d2 - d6) : m6 ? (e63 + e65) : denom;
    ds1 = (ds1 == 0.0f) ? 1.0f : ds1;
    float n2  = anym ? 0.0f : vc;
    float ds2 = anym ? 1.0f : ((denom == 0.0f) ? 1.0f : denom);

    float q1 = n1 / ds1;
    float q2 = n2 / ds2;
    float u = (1.0f - q1) - q2;

    w1 = m1 ? 1.0f : m2 ? 0.0f : m3 ? u    : m4 ? 0.0f : m5 ? u    : m6 ? 0.0f : u;
    w2 = m1 ? 0.0f : m2 ? 1.0f : m3 ? q1   : m4 ? 0.0f : m5 ? 0.0f : m6 ? u    : q1;
    w3 = m1 ? 0.0f : m2 ? 0.0f : m3 ? 0.0f : m4 ? 1.0f : m5 ? q1   : m6 ? q1   : q2;
}

__device__ __forceinline__ float tri_dist_region(
    float px, float py, float pz, const float* __restrict__ fd)
{
#pragma clang fp contract(off)
    const float ax = fd[0], ay = fd[1], az = fd[2];
    const float bx = fd[3], by = fd[4], bz = fd[5];
    const float cx = fd[6], cy = fd[7], cz = fd[8];
    const float abx = fd[9], aby = fd[10], abz = fd[11];
    const float acx = fd[12], acy = fd[13], acz = fd[14];
    const float daab = fd[15], daac = fd[16], dbab = fd[17];
    const float dbac = fd[18], dcab = fd[19], dcac = fd[20];

    float pab = fmaf(pz, abz, fmaf(py, aby, px * abx));
    float pac = fmaf(pz, acz, fmaf(py, acy, px * acx));

    float d1 = pab - daab;
    float d2 = pac - daac;
    float d3 = pab - dbab;
    float d4 = pac - dbac;
    float d5 = pab - dcab;
    float d6 = pac - dcac;

    float vc = d1 * d4 - d3 * d2;
    float vb = d5 * d2 - d1 * d6;
    float va = d3 * d6 - d5 * d4;

    float e63 = d4 - d3;
    float e65 = d5 - d6;
    float denom = (va + vb) + vc;

    float w1, w2, w3;
    region_w(d1, d2, d3, d4, d5, d6, va, vb, vc, e63, e65, denom, w1, w2, w3);

    float cpx = (w1 * ax + w2 * bx) + w3 * cx;
    float cpy = (w1 * ay + w2 * by) + w3 * cy;
    float cpz = (w1 * az + w2 * bz) + w3 * cz;
    float dx = px - cpx, dy = py - cpy, dz = pz - cpz;
    return (dx * dx + dy * dy) + dz * dz;
}

// =============== k_prep: const table + init ===============

__global__ __launch_bounds__(TPB) void k_prep(
    const float* __restrict__ vertices, const int* __restrict__ faces,
    float* __restrict__ tab, unsigned* __restrict__ minub,
    unsigned long long* __restrict__ best)
{
#pragma clang fp contract(off)
    int f = blockIdx.x * TPB + threadIdx.x;
    if (f < F_N) {
        float td[TW];
        face_setup(vertices, faces, f, td);
        float ax = td[0], ay = td[1], az = td[2];
        float abx = td[9], aby = td[10], abz = td[11];
        float acx = td[12], acy = td[13], acz = td[14];
        float nx = aby * acz - abz * acy;
        float ny = abz * acx - abx * acz;
        float nz = abx * acy - aby * acx;
        float nn = (nx * nx + ny * ny) + nz * nz;
        float abab = (abx * abx + aby * aby) + abz * abz;
        float acac = (acx * acx + acy * acy) + acz * acz;
        float L2v = abab + acac;
        bool bad = !(nn >= 1e-2f * L2v) || (nn < 1e-20f);
        td[21] = nx; td[22] = ny; td[23] = nz;
        td[24] = -((nx * ax + ny * ay) + nz * az);   // mnd
        td[25] = bad ? -1.0f : 1.0f / nn;            // inn (<0 marks bad)
        td[26] = 0.0f; td[27] = 0.0f; td[28] = 0.0f;
        td[29] = 0.0f; td[30] = 0.0f; td[31] = 0.0f;
#pragma unroll
        for (int k = 0; k < TW; k += 4)
            *(float4*)&tab[f * TW + k] = *(float4*)&td[k];
    }
    if (f < P_N) {
        minub[f] = 0x7f7f7f7fu;   // large positive float bits (indexed by SORTED slot)
        best[f] = ~0ull;          // (indexed by SORTED slot)
    }
}

// =============== k_sort: Morton bitonic (R9-proven) -> sorted float4(x,y,z,idx) ===============

__device__ __forceinline__ unsigned expand10(unsigned v)
{
    v &= 1023u;
    v = (v | (v << 16)) & 0x030000FFu;
    v = (v | (v << 8))  & 0x0300F00Fu;
    v = (v | (v << 4))  & 0x030C30C3u;
    v = (v | (v << 2))  & 0x09249249u;
    return v;
}

__global__ __launch_bounds__(1024) void k_sort(
    const float* __restrict__ points, float4* __restrict__ spts)
{
    __shared__ unsigned long long sk[P_N];
    const int t = threadIdx.x;

    for (int i = t; i < P_N; i += 1024) {
        float x = points[3 * i], y = points[3 * i + 1], z = points[3 * i + 2];
        auto q = [](float v) -> unsigned {
            float s = (v + 5.0f) * 102.4f;
            int u = (int)s;
            u = u < 0 ? 0 : (u > 1023 ? 1023 : u);
            return (unsigned)u;
        };
        unsigned key = (expand10(q(x)) << 2) | (expand10(q(y)) << 1) | expand10(q(z));
        sk[i] = ((unsigned long long)key << 32) | (unsigned)i;   // unique keys -> deterministic
    }

    for (unsigned k = 2; k <= P_N; k <<= 1) {
        for (unsigned jj = k >> 1; jj > 0; jj >>= 1) {
            __syncthreads();
            for (unsigned i = t; i < P_N; i += 1024) {
                unsigned ixj = i ^ jj;
                if (ixj > i) {
                    unsigned long long a = sk[i], b = sk[ixj];
                    bool up = ((i & k) == 0);
                    if (up ? (a > b) : (a < b)) { sk[i] = b; sk[ixj] = a; }
                }
            }
        }
    }
    __syncthreads();
    for (int i = t; i < P_N; i += 1024) {
        unsigned pi = (unsigned)(sk[i] & 0xffffffffull);
        spts[i] = make_float4(points[3 * pi], points[3 * pi + 1], points[3 * pi + 2],
                              __uint_as_float(pi));
    }
}

// =============== k_bound: single champion per tile, exact UB (slot-indexed) ===============

__global__ __launch_bounds__(TPB) void k_bound(
    const float4* __restrict__ spts,
    const float* __restrict__ tab,
    unsigned* __restrict__ minub)
{
#pragma clang fp contract(off)
    const int pblk = blockIdx.x, fblk = blockIdx.y, t = threadIdx.x;
    const int fbase = fblk * FPT;
    const int slot = pblk * TPB + t;
    float4 pt = spts[slot];
    const float px = pt.x, py = pt.y, pz = pt.z;

    float bestv = 1e30f;
    int bestj = fbase;

#pragma unroll 4
    for (int j = 0; j < FPT; ++j) {
        const float* __restrict__ tf = tab + (size_t)(fbase + j) * TW;
        float nx = tf[21], ny = tf[22], nz = tf[23], mnd = tf[24], inn = tf[25];
        float nd = fmaf(nz, pz, fmaf(ny, py, fmaf(nx, px, mnd)));
        float p2 = (nd * nd) * inn;
        bool better = (p2 >= 0.0f) & (p2 < bestv);   // excludes bad (<0) and NaN
        bestv = better ? p2 : bestv;
        bestj = better ? (fbase + j) : bestj;
    }

    float fd[21];
#pragma unroll
    for (int k = 0; k < 20; k += 4)
        *(float4*)&fd[k] = *(const float4*)&tab[(size_t)bestj * TW + k];
    fd[20] = tab[(size_t)bestj * TW + 20];
    float dist = tri_dist_region(px, py, pz, fd);
    if (!(dist != dist)) atomicMin(&minub[slot], __float_as_uint(dist));  // lane-contiguous
}

// =============== k_scan2: LB-pruned exact scan (sorted lanes, slot-indexed) ===============

__global__ __launch_bounds__(TPB) void k_scan2(
    const float4* __restrict__ spts,
    const float* __restrict__ tab,
    const unsigned* __restrict__ minub,
    unsigned long long* __restrict__ best)
{
#pragma clang fp contract(off)
    const int pblk = blockIdx.x, fblk = blockIdx.y, t = threadIdx.x;
    const int fbase = fblk * FPT;
    const int slot = pblk * TPB + t;
    float4 pt = spts[slot];
    const float px = pt.x, py = pt.y, pz = pt.z;
    const float thr = __uint_as_float(minub[slot]);

    unsigned bestdb = 0xffffffffu;
    int bestf = 0;

    for (int j = 0; j < FPT; ++j) {
        const float* __restrict__ tf = tab + (size_t)(fbase + j) * TW;
        float nx = tf[21], ny = tf[22], nz = tf[23], mnd = tf[24], inn = tf[25];
        float nd = fmaf(nz, pz, fmaf(ny, py, fmaf(nx, px, mnd)));
        float p2 = (nd * nd) * inn;                         // <0 for bad faces
        float lb = fmaxf(fmaf(p2, 0.97f, -1e-6f), 0.0f);    // sound LB (NaN -> 0)
        if (__any(lb <= thr)) {
            float dist = tri_dist_region(px, py, pz, tf);
            unsigned db = __float_as_uint(dist);
            if (dist != dist) db = 0u;   // NaN -> -inf (numpy argmin: first NaN wins)
            if (db < bestdb) { bestdb = db; bestf = fbase + j; }
        }
    }

    unsigned long long key =
        ((unsigned long long)bestdb << 32) | (unsigned)bestf;
    atomicMin(&best[slot], key);   // lane-contiguous
}

// =============== k_final: exact w's for winner; scatter to original index ===============

__global__ __launch_bounds__(TPB) void k_final(
    const float4* __restrict__ spts,
    const float* __restrict__ tab,
    const unsigned long long* __restrict__ best,
    float* __restrict__ out)
{
    const int slot = blockIdx.x * TPB + threadIdx.x;
    if (slot >= P_N) return;
    float4 pt = spts[slot];
    const int p = (int)__float_as_uint(pt.w);
    int f = (int)(best[slot] & 0x1fffull);

    float fd[21];
#pragma unroll
    for (int k = 0; k < 20; k += 4)
        *(float4*)&fd[k] = *(const float4*)&tab[(size_t)f * TW + k];
    fd[20] = tab[(size_t)f * TW + 20];

    float w1, w2, w3, dist;
    tri_eval_exact(pt.x, pt.y, pt.z, fd, w1, w2, w3, dist);
    out[p] = (float)f;
    out[P_N + p] = w1;
    out[2 * P_N + p] = w2;
    out[3 * P_N + p] = w3;
}

// =============== fallback: proven R5 full scan (tiny ws only) ===============

__global__ __launch_bounds__(TPB) void k_scan_full(
    const float* __restrict__ points,
    const float* __restrict__ vertices,
    const int* __restrict__ faces,
    unsigned long long* __restrict__ best)
{
#pragma clang fp contract(off)
    __shared__ float sq[21][FPT];
    const int pblk = blockIdx.x, fblk = blockIdx.y, t = threadIdx.x;
    if (t < FPT) {
        float fd[21];
        face_setup(vertices, faces, fblk * FPT + t, fd);
#pragma unroll
        for (int k = 0; k < 21; ++k) sq[k][t] = fd[k];
    }
    __syncthreads();

    const int p = pblk * TPB + t;
    const float px = points[3 * p], py = points[3 * p + 1], pz = points[3 * p + 2];
    const v2f pxv = {px, px}, pyv = {py, py}, pzv = {pz, pz};

    unsigned int bestdb = 0xffffffffu;
    int bestf = 0;
    const int fbase = fblk * FPT;

#pragma unroll 2
    for (int j = 0; j < FPT; j += 2) {
#define LD2(q) (*(const v2f*)&sq[q][j])
        v2f axv = LD2(0),  ayv = LD2(1),  azv = LD2(2);
        v2f bxv = LD2(3),  byv = LD2(4),  bzv = LD2(5);
        v2f cxv = LD2(6),  cyv = LD2(7),  czv = LD2(8);
        v2f abxv = LD2(9),  abyv = LD2(10), abzv = LD2(11);
        v2f acxv = LD2(12), acyv = LD2(13), aczv = LD2(14);
        v2f daabv = LD2(15), daacv = LD2(16), dbabv = LD2(17);
        v2f dbacv = LD2(18), dcabv = LD2(19), dcacv = LD2(20);
#undef LD2
        v2f pab = __builtin_elementwise_fma(pzv, abzv,
                    __builtin_elementwise_fma(pyv, abyv, pxv * abxv));
        v2f pac = __builtin_elementwise_fma(pzv, aczv,
                    __builtin_elementwise_fma(pyv, acyv, pxv * acxv));
        v2f d1 = pab - daabv, d2 = pac - daacv, d3 = pab - dbabv;
        v2f d4 = pac - dbacv, d5 = pab - dcabv, d6 = pac - dcacv;
        v2f vcv = d1 * d4 - d3 * d2;
        v2f vbv = d5 * d2 - d1 * d6;
        v2f vav = d3 * d6 - d5 * d4;
        v2f e63 = d4 - d3, e65 = d5 - d6;
        v2f denom = (vav + vbv) + vcv;

        float w1a, w2a, w3a, w1b, w2b, w3b;
        region_w(d1.x, d2.x, d3.x, d4.x, d5.x, d6.x,
                 vav.x, vbv.x, vcv.x, e63.x, e65.x, denom.x, w1a, w2a, w3a);
        region_w(d1.y, d2.y, d3.y, d4.y, d5.y, d6.y,
                 vav.y, vbv.y, vcv.y, e63.y, e65.y, denom.y, w1b, w2b, w3b);

        v2f w1v = {w1a, w1b}, w2v = {w2a, w2b}, w3v = {w3a, w3b};
        v2f cpx = (w1v * axv + w2v * bxv) + w3v * cxv;
        v2f cpy = (w1v * ayv + w2v * byv) + w3v * cyv;
        v2f cpz = (w1v * azv + w2v * bzv) + w3v * czv;
        v2f dx = pxv - cpx, dy = pyv - cpy, dz = pzv - cpz;
        v2f dist = (dx * dx + dy * dy) + dz * dz;

        float da = dist.x, db = dist.y;
        unsigned ua = __float_as_uint(da), ub = __float_as_uint(db);
        if (da != da) ua = 0u;
        if (db != db) ub = 0u;
        if (ua < bestdb) { bestdb = ua; bestf = fbase + j; }
        if (ub < bestdb) { bestdb = ub; bestf = fbase + j + 1; }
    }

    unsigned long long key =
        ((unsigned long long)bestdb << 32) | (unsigned int)bestf;
    atomicMin(&best[p], key);
}

__global__ __launch_bounds__(TPB) void k_final_fb(
    const float* __restrict__ points,
    const float* __restrict__ vertices,
    const int* __restrict__ faces,
    const unsigned long long* __restrict__ best,
    float* __restrict__ out)
{
    const int p = blockIdx.x * TPB + threadIdx.x;
    if (p >= P_N) return;
    int f = (int)(best[p] & 0x1fffull);
    float fd[21];
    face_setup(vertices, faces, f, fd);
    float w1, w2, w3, dist;
    tri_eval_exact(points[3 * p], points[3 * p + 1], points[3 * p + 2],
                   fd, w1, w2, w3, dist);
    out[p] = (float)f;
    out[P_N + p] = w1;
    out[2 * P_N + p] = w2;
    out[3 * P_N + p] = w3;
}

extern "C" void kernel_launch(void* const* d_in, const int* in_sizes, int n_in,
                              void* d_out, int out_size, void* d_ws, size_t ws_size,
                              hipStream_t stream)
{
    const float* points = (const float*)d_in[0];
    const float* vertices = (const float*)d_in[1];
    const int* faces = (const int*)d_in[2];
    float* out = (float*)d_out;
    char* ws = (char*)d_ws;

    if (ws_size >= WS_NEEDED) {
        float* tab = (float*)ws;
        unsigned* minub = (unsigned*)(ws + WS_MINUB_OFF);
        unsigned long long* best = (unsigned long long*)(ws + WS_BEST_OFF);
        float4* spts = (float4*)(ws + WS_SPTS_OFF);

        k_prep<<<F_N / TPB, TPB, 0, stream>>>(vertices, faces, tab, minub, best);
        k_sort<<<1, 1024, 0, stream>>>(points, spts);
        k_bound<<<dim3(P_N / TPB, NT), TPB, 0, stream>>>(spts, tab, minub);
        k_scan2<<<dim3(P_N / TPB, NT), TPB, 0, stream>>>(spts, tab, minub, best);
        k_final<<<(P_N + TPB - 1) / TPB, TPB, 0, stream>>>(spts, tab, best, out);
    } else {
        unsigned long long* best = (unsigned long long*)ws;
        hipMemsetAsync(best, 0xFF, P_N * sizeof(unsigned long long), stream);
        k_scan_full<<<dim3(P_N / TPB, NT), TPB, 0, stream>>>(points, vertices, faces, best);
        k_final_fb<<<(P_N + TPB - 1) / TPB, TPB, 0, stream>>>(points, vertices, faces, best, out);
    }
}

// Round 13
// 60.767 us; speedup vs baseline: 2.7294x; 1.4491x over previous
//
#include <hip/hip_runtime.h>
#include <cstdint>

#pragma clang fp contract(off)

typedef float v2f __attribute__((ext_vector_type(2)));

#define P_N 2048
#define F_N 8192
#define TPB 256
#define FPT 32
#define NT (F_N / FPT)
#define BT 64                 // k_bound champion tile
#define NBT (F_N / BT)
#define TW 32
#define NBKT 512              // counting-sort buckets

// ---- workspace layout ----
#define WS_PTAB_OFF  ((size_t)F_N * TW * 4)            // tab = 1 MB
#define WS_MINUB_OFF (WS_PTAB_OFF + (size_t)F_N * 16)  // ptab 128 KB
#define WS_BEST_OFF  (WS_MINUB_OFF + P_N * 4)
#define WS_SPTS_OFF  (WS_BEST_OFF + P_N * 8)
#define WS_NEEDED    (WS_SPTS_OFF + P_N * 16)

// =============== exact helpers (bit-identical to reference, proven R1-R12) ===============

__device__ __forceinline__ void face_setup(
    const float* __restrict__ vertices, const int* __restrict__ faces, int f,
    float* fd)
{
#pragma clang fp contract(off)
    int i0 = faces[3 * f + 0];
    int i1 = faces[3 * f + 1];
    int i2 = faces[3 * f + 2];
    float ax = vertices[3 * i0 + 0], ay = vertices[3 * i0 + 1], az = vertices[3 * i0 + 2];
    float bx = vertices[3 * i1 + 0], by = vertices[3 * i1 + 1], bz = vertices[3 * i1 + 2];
    float cx = vertices[3 * i2 + 0], cy = vertices[3 * i2 + 1], cz = vertices[3 * i2 + 2];
    float abx = bx - ax, aby = by - ay, abz = bz - az;
    float acx = cx - ax, acy = cy - ay, acz = cz - az;
    float daab = (ax * abx + ay * aby) + az * abz;
    float daac = (ax * acx + ay * acy) + az * acz;
    float dbab = (bx * abx + by * aby) + bz * abz;
    float dbac = (bx * acx + by * acy) + bz * acz;
    float dcab = (cx * abx + cy * aby) + cz * abz;
    float dcac = (cx * acx + cy * acy) + cz * acz;
    fd[0] = ax;  fd[1] = ay;  fd[2] = az;
    fd[3] = bx;  fd[4] = by;  fd[5] = bz;
    fd[6] = cx;  fd[7] = cy;  fd[8] = cz;
    fd[9] = abx; fd[10] = aby; fd[11] = abz;
    fd[12] = acx; fd[13] = acy; fd[14] = acz;
    fd[15] = daab; fd[16] = daac; fd[17] = dbab;
    fd[18] = dbac; fd[19] = dcab; fd[20] = dcac;
}

__device__ __forceinline__ void tri_eval_exact(
    float px, float py, float pz,
    const float* __restrict__ fd,
    float& w1o, float& w2o, float& w3o, float& disto)
{
#pragma clang fp contract(off)
    const float ax = fd[0], ay = fd[1], az = fd[2];
    const float bx = fd[3], by = fd[4], bz = fd[5];
    const float cx = fd[6], cy = fd[7], cz = fd[8];
    const float abx = fd[9], aby = fd[10], abz = fd[11];
    const float acx = fd[12], acy = fd[13], acz = fd[14];
    const float daab = fd[15], daac = fd[16], dbab = fd[17];
    const float dbac = fd[18], dcab = fd[19], dcac = fd[20];

    float pab = fmaf(pz, abz, fmaf(py, aby, px * abx));
    float pac = fmaf(pz, acz, fmaf(py, acy, px * acx));

    float d1 = pab - daab;
    float d2 = pac - daac;
    float d3 = pab - dbab;
    float d4 = pac - dbac;
    float d5 = pab - dcab;
    float d6 = pac - dcac;

    float vc = d1 * d4 - d3 * d2;
    float vb = d5 * d2 - d1 * d6;
    float va = d3 * d6 - d5 * d4;

    float denom = (va + vb) + vc;
    float dn = (denom == 0.0f) ? 1.0f : denom;
    float v7 = vb / dn;
    float w7 = vc / dn;
    float w1 = (1.0f - v7) - w7;
    float w2 = v7;
    float w3 = w7;

    float e63 = d4 - d3;
    float e65 = d5 - d6;
    float t6d = e63 + e65; t6d = (t6d == 0.0f) ? 1.0f : t6d;
    float t6 = e63 / t6d;
    if ((va <= 0.0f) & (e63 >= 0.0f) & (e65 >= 0.0f)) { w1 = 0.0f; w2 = 1.0f - t6; w3 = t6; }

    float t5d = d2 - d6; t5d = (t5d == 0.0f) ? 1.0f : t5d;
    float t5 = d2 / t5d;
    if ((vb <= 0.0f) & (d2 >= 0.0f) & (d6 <= 0.0f)) { w1 = 1.0f - t5; w2 = 0.0f; w3 = t5; }

    if ((d6 >= 0.0f) & (d5 <= d6)) { w1 = 0.0f; w2 = 0.0f; w3 = 1.0f; }

    float t3d = d1 - d3; t3d = (t3d == 0.0f) ? 1.0f : t3d;
    float t3 = d1 / t3d;
    if ((vc <= 0.0f) & (d1 >= 0.0f) & (d3 <= 0.0f)) { w1 = 1.0f - t3; w2 = t3; w3 = 0.0f; }

    if ((d3 >= 0.0f) & (d4 <= d3)) { w1 = 0.0f; w2 = 1.0f; w3 = 0.0f; }

    if ((d1 <= 0.0f) & (d2 <= 0.0f)) { w1 = 1.0f; w2 = 0.0f; w3 = 0.0f; }

    float cpx = (w1 * ax + w2 * bx) + w3 * cx;
    float cpy = (w1 * ay + w2 * by) + w3 * cy;
    float cpz = (w1 * az + w2 * bz) + w3 * cz;
    float dx = px - cpx, dy = py - cpy, dz = pz - cpz;
    float dist = (dx * dx + dy * dy) + dz * dz;

    w1o = w1; w2o = w2; w3o = w3; disto = dist;
}

__device__ __forceinline__ void region_w(
    float d1, float d2, float d3, float d4, float d5, float d6,
    float va, float vb, float vc, float e63, float e65, float denom,
    float& w1, float& w2, float& w3)
{
#pragma clang fp contract(off)
    bool m1 = (d1 <= 0.0f) & (d2 <= 0.0f);
    bool m2 = (d3 >= 0.0f) & (d4 <= d3);
    bool m3 = (vc <= 0.0f) & (d1 >= 0.0f) & (d3 <= 0.0f);
    bool m4 = (d6 >= 0.0f) & (d5 <= d6);
    bool m5 = (vb <= 0.0f) & (d2 >= 0.0f) & (d6 <= 0.0f);
    bool m6 = (va <= 0.0f) & (e63 >= 0.0f) & (e65 >= 0.0f);
    bool anym = m1 | m2 | m3 | m4 | m5 | m6;

    float n1  = m1 ? 0.0f : m2 ? 0.0f : m3 ? d1        : m4 ? 0.0f : m5 ? d2        : m6 ? e63         : vb;
    float ds1 = m1 ? 1.0f : m2 ? 1.0f : m3 ? (d1 - d3) : m4 ? 1.0f : m5 ? (d2 - d6) : m6 ? (e63 + e65) : denom;
    ds1 = (ds1 == 0.0f) ? 1.0f : ds1;
    float n2  = anym ? 0.0f : vc;
    float ds2 = anym ? 1.0f : ((denom == 0.0f) ? 1.0f : denom);

    float q1 = n1 / ds1;
    float q2 = n2 / ds2;
    float u = (1.0f - q1) - q2;

    w1 = m1 ? 1.0f : m2 ? 0.0f : m3 ? u    : m4 ? 0.0f : m5 ? u    : m6 ? 0.0f : u;
    w2 = m1 ? 0.0f : m2 ? 1.0f : m3 ? q1   : m4 ? 0.0f : m5 ? 0.0f : m6 ? u    : q1;
    w3 = m1 ? 0.0f : m2 ? 0.0f : m3 ? 0.0f : m4 ? 1.0f : m5 ? q1   : m6 ? q1   : q2;
}

__device__ __forceinline__ float tri_dist_region(
    float px, float py, float pz, const float* __restrict__ fd)
{
#pragma clang fp contract(off)
    const float ax = fd[0], ay = fd[1], az = fd[2];
    const float bx = fd[3], by = fd[4], bz = fd[5];
    const float cx = fd[6], cy = fd[7], cz = fd[8];
    const float abx = fd[9], aby = fd[10], abz = fd[11];
    const float acx = fd[12], acy = fd[13], acz = fd[14];
    const float daab = fd[15], daac = fd[16], dbab = fd[17];
    const float dbac = fd[18], dcab = fd[19], dcac = fd[20];

    float pab = fmaf(pz, abz, fmaf(py, aby, px * abx));
    float pac = fmaf(pz, acz, fmaf(py, acy, px * acx));

    float d1 = pab - daab;
    float d2 = pac - daac;
    float d3 = pab - dbab;
    float d4 = pac - dbac;
    float d5 = pab - dcab;
    float d6 = pac - dcac;

    float vc = d1 * d4 - d3 * d2;
    float vb = d5 * d2 - d1 * d6;
    float va = d3 * d6 - d5 * d4;

    float e63 = d4 - d3;
    float e65 = d5 - d6;
    float denom = (va + vb) + vc;

    float w1, w2, w3;
    region_w(d1, d2, d3, d4, d5, d6, va, vb, vc, e63, e65, denom, w1, w2, w3);

    float cpx = (w1 * ax + w2 * bx) + w3 * cx;
    float cpy = (w1 * ay + w2 * by) + w3 * cy;
    float cpz = (w1 * az + w2 * bz) + w3 * cz;
    float dx = px - cpx, dy = py - cpy, dz = pz - cpz;
    return (dx * dx + dy * dy) + dz * dz;
}

// =============== k_prep: const table + unit-plane table + init ===============

__global__ __launch_bounds__(TPB) void k_prep(
    const float* __restrict__ vertices, const int* __restrict__ faces,
    float* __restrict__ tab, float4* __restrict__ ptab,
    unsigned* __restrict__ minub, unsigned long long* __restrict__ best)
{
#pragma clang fp contract(off)
    int f = blockIdx.x * TPB + threadIdx.x;
    if (f < F_N) {
        float td[TW];
        face_setup(vertices, faces, f, td);
        float ax = td[0], ay = td[1], az = td[2];
        float abx = td[9], aby = td[10], abz = td[11];
        float acx = td[12], acy = td[13], acz = td[14];
        float nx = aby * acz - abz * acy;
        float ny = abz * acx - abx * acz;
        float nz = abx * acy - aby * acx;
        float nn = (nx * nx + ny * ny) + nz * nz;
        float abab = (abx * abx + aby * aby) + abz * abz;
        float acac = (acx * acx + acy * acy) + acz * acz;
        float L2v = abab + acac;
        bool bad = !(nn >= 1e-2f * L2v) || (nn < 1e-20f);
        float mnd = -((nx * ax + ny * ay) + nz * az);
        float s = bad ? 0.0f : (1.0f / sqrtf(nn));
        // unit plane: nd = n̂.p + d̂ ; bad -> zeros -> p2 = 0 (always candidate)
        ptab[f] = make_float4(nx * s, ny * s, nz * s, mnd * s);

        td[21] = 0.0f; td[22] = 0.0f; td[23] = 0.0f; td[24] = 0.0f; td[25] = 0.0f;
        td[26] = 0.0f; td[27] = 0.0f; td[28] = 0.0f;
        td[29] = 0.0f; td[30] = 0.0f; td[31] = 0.0f;
#pragma unroll
        for (int k = 0; k < TW; k += 4)
            *(float4*)&tab[f * TW + k] = *(float4*)&td[k];
    }
    if (f < P_N) {
        minub[f] = 0x7f7f7f7fu;   // large positive float bits (slot-indexed)
        best[f] = ~0ull;
    }
}

// =============== k_csort: 512-bucket Morton counting sort ===============

__device__ __forceinline__ unsigned ex3(unsigned v)
{
    return (v & 1u) | ((v & 2u) << 2) | ((v & 4u) << 4);
}

__device__ __forceinline__ unsigned morton9(float x, float y, float z)
{
    auto q = [](float v) -> unsigned {
        int u = (int)(v + 4.0f);
        u = u < 0 ? 0 : (u > 7 ? 7 : u);
        return (unsigned)u;
    };
    return (ex3(q(x)) << 2) | (ex3(q(y)) << 1) | ex3(q(z));
}

__global__ __launch_bounds__(1024) void k_csort(
    const float* __restrict__ points, float4* __restrict__ spts)
{
    __shared__ unsigned hist[NBKT];
    __shared__ unsigned scn[NBKT];
    const int t = threadIdx.x;

    if (t < NBKT) hist[t] = 0;
    __syncthreads();

    for (int i = t; i < P_N; i += 1024) {
        float x = points[3 * i], y = points[3 * i + 1], z = points[3 * i + 2];
        atomicAdd(&hist[morton9(x, y, z)], 1u);
    }
    __syncthreads();

    if (t < NBKT) scn[t] = hist[t];
    __syncthreads();
    for (int off = 1; off < NBKT; off <<= 1) {
        unsigned v = 0;
        if (t < NBKT && t >= off) v = scn[t - off];
        __syncthreads();
        if (t < NBKT) scn[t] += v;
        __syncthreads();
    }
    if (t < NBKT) hist[t] = scn[t] - hist[t];   // exclusive base, reused as cursor
    __syncthreads();

    for (int i = t; i < P_N; i += 1024) {
        float x = points[3 * i], y = points[3 * i + 1], z = points[3 * i + 2];
        unsigned slot = atomicAdd(&hist[morton9(x, y, z)], 1u);
        spts[slot] = make_float4(x, y, z, __uint_as_float((unsigned)i));
    }
}

// =============== k_bound: champion per 64-face tile, exact UB (slot-indexed) ===============

__global__ __launch_bounds__(TPB) void k_bound(
    const float4* __restrict__ spts,
    const float* __restrict__ tab,
    const float4* __restrict__ ptab,
    unsigned* __restrict__ minub)
{
#pragma clang fp contract(off)
    const int pblk = blockIdx.x, fblk = blockIdx.y, t = threadIdx.x;
    const int fbase = fblk * BT;
    const int slot = pblk * TPB + t;
    float4 pt = spts[slot];
    const float px = pt.x, py = pt.y, pz = pt.z;

    float bestv = 1e30f;
    int bestj = fbase;

#pragma unroll 4
    for (int j = 0; j < BT; ++j) {
        float4 pl = ptab[fbase + j];          // block-uniform -> scalar load
        float nd = fmaf(pl.z, pz, fmaf(pl.y, py, fmaf(pl.x, px, pl.w)));
        float p2 = nd * nd;
        bool better = p2 < bestv;             // NaN -> false
        bestv = better ? p2 : bestv;
        bestj = better ? (fbase + j) : bestj;
    }

    float fd[21];
#pragma unroll
    for (int k = 0; k < 20; k += 4)
        *(float4*)&fd[k] = *(const float4*)&tab[(size_t)bestj * TW + k];
    fd[20] = tab[(size_t)bestj * TW + 20];
    float dist = tri_dist_region(px, py, pz, fd);
    if (!(dist != dist)) atomicMin(&minub[slot], __float_as_uint(dist));
}

// =============== k_scan2: LB-pruned exact scan (sorted lanes, slot-indexed) ===============

__global__ __launch_bounds__(TPB) void k_scan2(
    const float4* __restrict__ spts,
    const float* __restrict__ tab,
    const float4* __restrict__ ptab,
    const unsigned* __restrict__ minub,
    unsigned long long* __restrict__ best)
{
#pragma clang fp contract(off)
    const int pblk = blockIdx.x, fblk = blockIdx.y, t = threadIdx.x;
    const int fbase = fblk * FPT;
    const int slot = pblk * TPB + t;
    float4 pt = spts[slot];
    const float px = pt.x, py = pt.y, pz = pt.z;
    const float thr = __uint_as_float(minub[slot]);

    unsigned bestdb = 0xffffffffu;
    int bestf = 0;

    for (int j = 0; j < FPT; ++j) {
        float4 pl = ptab[fbase + j];          // block-uniform -> scalar load
        float nd = fmaf(pl.z, pz, fmaf(pl.y, py, fmaf(pl.x, px, pl.w)));
        float p2 = nd * nd;                   // 0 for bad faces
        float lb = fmaxf(fmaf(p2, 0.97f, -1e-6f), 0.0f);   // sound LB (NaN -> 0)
        if (__any(lb <= thr)) {
            const float* __restrict__ tf = tab + (size_t)(fbase + j) * TW;
            float dist = tri_dist_region(px, py, pz, tf);
            unsigned db = __float_as_uint(dist);
            if (dist != dist) db = 0u;        // NaN -> -inf (numpy first-NaN wins)
            if (db < bestdb) { bestdb = db; bestf = fbase + j; }
        }
    }

    unsigned long long key =
        ((unsigned long long)bestdb << 32) | (unsigned)bestf;
    atomicMin(&best[slot], key);
}

// =============== k_final: exact w's for winner; scatter to original index ===============

__global__ __launch_bounds__(TPB) void k_final(
    const float4* __restrict__ spts,
    const float* __restrict__ tab,
    const unsigned long long* __restrict__ best,
    float* __restrict__ out)
{
    const int slot = blockIdx.x * TPB + threadIdx.x;
    if (slot >= P_N) return;
    float4 pt = spts[slot];
    const int p = (int)__float_as_uint(pt.w);
    int f = (int)(best[slot] & 0x1fffull);

    float fd[21];
#pragma unroll
    for (int k = 0; k < 20; k += 4)
        *(float4*)&fd[k] = *(const float4*)&tab[(size_t)f * TW + k];
    fd[20] = tab[(size_t)f * TW + 20];

    float w1, w2, w3, dist;
    tri_eval_exact(pt.x, pt.y, pt.z, fd, w1, w2, w3, dist);
    out[p] = (float)f;
    out[P_N + p] = w1;
    out[2 * P_N + p] = w2;
    out[3 * P_N + p] = w3;
}

// =============== fallback: proven R5 full scan (tiny ws only) ===============

__global__ __launch_bounds__(TPB) void k_scan_full(
    const float* __restrict__ points,
    const float* __restrict__ vertices,
    const int* __restrict__ faces,
    unsigned long long* __restrict__ best)
{
#pragma clang fp contract(off)
    __shared__ float sq[21][FPT];
    const int pblk = blockIdx.x, fblk = blockIdx.y, t = threadIdx.x;
    if (t < FPT) {
        float fd[21];
        face_setup(vertices, faces, fblk * FPT + t, fd);
#pragma unroll
        for (int k = 0; k < 21; ++k) sq[k][t] = fd[k];
    }
    __syncthreads();

    const int p = pblk * TPB + t;
    const float px = points[3 * p], py = points[3 * p + 1], pz = points[3 * p + 2];
    const v2f pxv = {px, px}, pyv = {py, py}, pzv = {pz, pz};

    unsigned int bestdb = 0xffffffffu;
    int bestf = 0;
    const int fbase = fblk * FPT;

#pragma unroll 2
    for (int j = 0; j < FPT; j += 2) {
#define LD2(q) (*(const v2f*)&sq[q][j])
        v2f axv = LD2(0),  ayv = LD2(1),  azv = LD2(2);
        v2f bxv = LD2(3),  byv = LD2(4),  bzv = LD2(5);
        v2f cxv = LD2(6),  cyv = LD2(7),  czv = LD2(8);
        v2f abxv = LD2(9),  abyv = LD2(10), abzv = LD2(11);
        v2f acxv = LD2(12), acyv = LD2(13), aczv = LD2(14);
        v2f daabv = LD2(15), daacv = LD2(16), dbabv = LD2(17);
        v2f dbacv = LD2(18), dcabv = LD2(19), dcacv = LD2(20);
#undef LD2
        v2f pab = __builtin_elementwise_fma(pzv, abzv,
                    __builtin_elementwise_fma(pyv, abyv, pxv * abxv));
        v2f pac = __builtin_elementwise_fma(pzv, aczv,
                    __builtin_elementwise_fma(pyv, acyv, pxv * acxv));
        v2f d1 = pab - daabv, d2 = pac - daacv, d3 = pab - dbabv;
        v2f d4 = pac - dbacv, d5 = pab - dcabv, d6 = pac - dcacv;
        v2f vcv = d1 * d4 - d3 * d2;
        v2f vbv = d5 * d2 - d1 * d6;
        v2f vav = d3 * d6 - d5 * d4;
        v2f e63 = d4 - d3, e65 = d5 - d6;
        v2f denom = (vav + vbv) + vcv;

        float w1a, w2a, w3a, w1b, w2b, w3b;
        region_w(d1.x, d2.x, d3.x, d4.x, d5.x, d6.x,
                 vav.x, vbv.x, vcv.x, e63.x, e65.x, denom.x, w1a, w2a, w3a);
        region_w(d1.y, d2.y, d3.y, d4.y, d5.y, d6.y,
                 vav.y, vbv.y, vcv.y, e63.y, e65.y, denom.y, w1b, w2b, w3b);

        v2f w1v = {w1a, w1b}, w2v = {w2a, w2b}, w3v = {w3a, w3b};
        v2f cpx = (w1v * axv + w2v * bxv) + w3v * cxv;
        v2f cpy = (w1v * ayv + w2v * byv) + w3v * cyv;
        v2f cpz = (w1v * azv + w2v * bzv) + w3v * czv;
        v2f dx = pxv - cpx, dy = pyv - cpy, dz = pzv - cpz;
        v2f dist = (dx * dx + dy * dy) + dz * dz;

        float da = dist.x, db = dist.y;
        unsigned ua = __float_as_uint(da), ub = __float_as_uint(db);
        if (da != da) ua = 0u;
        if (db != db) ub = 0u;
        if (ua < bestdb) { bestdb = ua; bestf = fbase + j; }
        if (ub < bestdb) { bestdb = ub; bestf = fbase + j + 1; }
    }

    unsigned long long key =
        ((unsigned long long)bestdb << 32) | (unsigned int)bestf;
    atomicMin(&best[p], key);
}

__global__ __launch_bounds__(TPB) void k_final_fb(
    const float* __restrict__ points,
    const float* __restrict__ vertices,
    const int* __restrict__ faces,
    const unsigned long long* __restrict__ best,
    float* __restrict__ out)
{
    const int p = blockIdx.x * TPB + threadIdx.x;
    if (p >= P_N) return;
    int f = (int)(best[p] & 0x1fffull);
    float fd[21];
    face_setup(vertices, faces, f, fd);
    float w1, w2, w3, dist;
    tri_eval_exact(points[3 * p], points[3 * p + 1], points[3 * p + 2],
                   fd, w1, w2, w3, dist);
    out[p] = (float)f;
    out[P_N + p] = w1;
    out[2 * P_N + p] = w2;
    out[3 * P_N + p] = w3;
}

extern "C" void kernel_launch(void* const* d_in, const int* in_sizes, int n_in,
                              void* d_out, int out_size, void* d_ws, size_t ws_size,
                              hipStream_t stream)
{
    const float* points = (const float*)d_in[0];
    const float* vertices = (const float*)d_in[1];
    const int* faces = (const int*)d_in[2];
    float* out = (float*)d_out;
    char* ws = (char*)d_ws;

    if (ws_size >= WS_NEEDED) {
        float* tab = (float*)ws;
        float4* ptab = (float4*)(ws + WS_PTAB_OFF);
        unsigned* minub = (unsigned*)(ws + WS_MINUB_OFF);
        unsigned long long* best = (unsigned long long*)(ws + WS_BEST_OFF);
        float4* spts = (float4*)(ws + WS_SPTS_OFF);

        k_prep<<<F_N / TPB, TPB, 0, stream>>>(vertices, faces, tab, ptab, minub, best);
        k_csort<<<1, 1024, 0, stream>>>(points, spts);
        k_bound<<<dim3(P_N / TPB, NBT), TPB, 0, stream>>>(spts, tab, ptab, minub);
        k_scan2<<<dim3(P_N / TPB, NT), TPB, 0, stream>>>(spts, tab, ptab, minub, best);
        k_final<<<(P_N + TPB - 1) / TPB, TPB, 0, stream>>>(spts, tab, best, out);
    } else {
        unsigned long long* best = (unsigned long long*)ws;
        hipMemsetAsync(best, 0xFF, P_N * sizeof(unsigned long long), stream);
        k_scan_full<<<dim3(P_N / TPB, NT), TPB, 0, stream>>>(points, vertices, faces, best);
        k_final_fb<<<(P_N + TPB - 1) / TPB, TPB, 0, stream>>>(points, vertices, faces, best, out);
    }
}